// Round 4
// baseline (419.349 us; speedup 1.0000x reference)
//
#include <hip/hip_runtime.h>

// WindowAttention MFMA v6 (fused): B=32, 56x56, C=192, heads=6, d=32, ws=7, NW=49
//  ln:   prep folded + LayerNorm -> xng COMPACT (49 rows/window, row-swizzled bf16)
//        stored in d_ws (same 38.5MB slot the attn intermediate used to occupy).
//        One block per window -> wi->XCD map matches k1 (producer/consumer L2 affinity).
//  k1:   ONE block per window (2048 blocks, 6 waves). Full fusion:
//        stage xn (glds16, rows 0..47 = 18 chunks exactly; row 48 reg-staged;
//        rows 49..63 zero-filled) ->
//        QKV trio0 (acc0) -> epi0 -> QKV trio1 (acc1 HELD IN REGS) ->
//        attn round0 -> O0 into ob (freed xn buffer, stride 104) -> epi1 + proj K0..95 ->
//        attn round1 -> O1 into ob -> proj K96..191 -> fp32 out (window reverse).
//        Deletes k2 + 116MB attn round-trip. LDS 64.5KB -> 2 blocks/CU, VGPR cap 170.

typedef __bf16 bf16x8 __attribute__((ext_vector_type(8)));
typedef float  f32x4  __attribute__((ext_vector_type(4)));
typedef unsigned int u32;
union U128 { uint4 u; bf16x8 v; };

__device__ __forceinline__ f32x4 mfma16(bf16x8 a, bf16x8 b, f32x4 c){
  return __builtin_amdgcn_mfma_f32_16x16x32_bf16(a, b, c, 0, 0, 0);
}
__device__ __forceinline__ f32x4 f4zero(){
  f32x4 z; z[0]=0.f; z[1]=0.f; z[2]=0.f; z[3]=0.f; return z;
}
__device__ __forceinline__ unsigned short f2bf(float f){
  union{float f; unsigned int i;} x; x.f = f;
  unsigned int r = x.i + 0x7fffu + ((x.i >> 16) & 1u);  // RNE
  return (unsigned short)(r >> 16);
}
__device__ __forceinline__ bf16x8 ldfrag(const unsigned short* p){
  U128 x; x.u = *(const uint4*)p; return x.v;
}
__device__ __forceinline__ int div7(int t){ return (t * 9363) >> 16; }  // exact for t<64

// async 16B/lane global -> LDS (wave-uniform LDS base + lane*16)
__device__ __forceinline__ void glds16(const unsigned short* g, unsigned short* l){
  __builtin_amdgcn_global_load_lds((const __attribute__((address_space(1))) u32*)g,
                                   (__attribute__((address_space(3))) u32*)l, 16, 0, 0);
}

// ---------------- ln: prep (folded) + LayerNorm + window partition -> xng ----------------
// grid 2048 (one block per window) x 256 (4 waves); rows t = wave, wave+4, ...
// xng[(wi*49 + t)*192], each row XOR-swizzled: short idx ^= (t&7)<<3.
__global__ __launch_bounds__(256, 8) void wa_ln(
    const float* __restrict__ x, const float* __restrict__ gamma,
    unsigned short* __restrict__ xng,
    const float* __restrict__ qkv_w, const float* __restrict__ proj_w,
    const float* __restrict__ rpb,
    unsigned short* __restrict__ wq, unsigned short* __restrict__ wp,
    float* __restrict__ bt)
{
  const int tid = threadIdx.x;

  // --- folded prep (first 432 blocks) ---
  if (blockIdx.x < 432){
    int i = blockIdx.x * 256 + tid;
    if (i < 576*192) wq[i] = f2bf(qkv_w[i]);
    if (i < 192*192) wp[i] = f2bf(proj_w[i]);
    if (i < 6*64*64){
      // btT layout: [head][t][l16][nt] so one lane reads 4 bias values as a dwordx4
      int head = i >> 12, t = (i >> 6) & 63, j = i & 63;
      int l16 = j >> 2, nt = j & 3;
      int col = nt*16 + l16;
      float v;
      if (t < 49 && col < 49){
        int tr = div7(t),   tc = t   - tr*7;
        int jr = div7(col), jc = col - jr*7;
        v = rpb[((tr - jr + 6)*13 + (tc - jc + 6))*6 + head];
      } else {
        v = (col >= 49) ? -3.0e38f : 0.0f;  // mask folded into bias
      }
      bt[i] = v;
    }
  }

  // --- LayerNorm, one window per block ---
  const int wave = tid >> 6, lane = tid & 63;
  const int wi = blockIdx.x;
  const int b = wi >> 6, wrr = (wi >> 3) & 7, wcc = wi & 7;
  const float g0 = gamma[lane], g1 = gamma[lane+64], g2 = gamma[lane+128];
  const float* xb = x + (size_t)b * 3136 * 192;

  for (int t = wave; t < 49; t += 4){
    const int tr = div7(t), tc = t - tr*7;
    const float* xt = xb + (size_t)((wrr*7 + tr)*56 + wcc*7 + tc) * 192;
    float v0 = xt[lane], v1 = xt[lane+64], v2 = xt[lane+128];
    float s  = v0 + v1 + v2;
    float sq = v0*v0 + v1*v1 + v2*v2;
#pragma unroll
    for (int off = 32; off > 0; off >>= 1){
      s  += __shfl_xor(s,  off);
      sq += __shfl_xor(sq, off);
    }
    float mu  = s * (1.0f/192.0f);
    float var = sq * (1.0f/192.0f) - mu*mu;
    float inv = rsqrtf(var + 1e-5f);
    unsigned short* dst = xng + ((size_t)wi*49 + t) * 192;
    const int sw = (t & 7) << 3;
    dst[lane        ^ sw] = f2bf((v0 - mu)*inv*g0);
    dst[(lane + 64) ^ sw] = f2bf((v1 - mu)*inv*g1);
    dst[(lane + 128)^ sw] = f2bf((v2 - mu)*inv*g2);
  }
}

// ---------------- k1: fused QKV + attention + proj ----------------
// grid 2048 (one block per window); block 384 (6 waves); LDS 64.5KB -> 2 blocks/CU
#define OBS 104   // ob stride in shorts (208B = 52 dwords -> 2-way bank aliasing, free)
__global__ __launch_bounds__(384, 3) void wa_k1(
    const unsigned short* __restrict__ xng, const float* __restrict__ bt,
    const unsigned short* __restrict__ wq, const float* __restrict__ qkv_b,
    const unsigned short* __restrict__ wp, const float* __restrict__ pb,
    float* __restrict__ out)
{
  __shared__ __align__(16) unsigned short qk[3*64*72];   // Q|K trio (P overlays)  27648B
  __shared__ __align__(16) unsigned short vt[3*32*72];   // V^T trio              13824B
  __shared__ __align__(16) unsigned short xnb[64*192];   // xn tile; later ob[64][OBS] 24576B

  const int wi   = blockIdx.x;
  const int b    = wi >> 6;
  const int wr   = (wi >> 3) & 7;
  const int wc   = wi & 7;
  const int tid  = threadIdx.x;
  const int wave = tid >> 6;
  const int lane = tid & 63;
  const int quad = lane >> 4;
  const int l16  = lane & 15;
  const int sec  = wave >> 1, sub = wave & 1;   // QKV roles
  const int hl   = wave >> 1, half = wave & 1;  // attention roles

  unsigned short* const ob = xnb;               // O buffer overlay [64][OBS]

  // proj bias prefetch (2 scalars)
  const float pbv0 = pb[wave*32 + l16];
  const float pbv1 = pb[wave*32 + 16 + l16];

  // ---- stage xn: rows 0..47 via glds16 (18 chunks exactly), row 48 reg, 49..63 zero ----
  const unsigned short* xw = xng + (size_t)wi * 49 * 192;
  {
    const uint4 z = {0u,0u,0u,0u};
    for (int i = tid; i < 360; i += 384) *(uint4*)&xnb[9408 + i*8] = z;  // rows 49..63
    uint4 r48;
    if (tid < 24) r48 = *(const uint4*)(xw + 9216 + tid*8);              // row 48
#pragma unroll
    for (int j = 0; j < 3; j++){
      const int chunk = wave*3 + j;                                      // 0..17
      glds16(xw + chunk*512 + lane*8, &xnb[chunk*512]);
    }
    if (tid < 24) *(uint4*)&xnb[9216 + tid*8] = r48;
  }
  __syncthreads();   // SYNC1: xn staged (vmcnt+lgkm drained)

  // ---- QKV GEMM for trio np: wave -> sec(q/k/v), 48 cols ----
  auto qkv_gemm = [&](f32x4 (*acc)[3], int np){
    const int n0 = sec*192 + np*96 + sub*48;
#pragma unroll
    for (int mt = 0; mt < 4; mt++)
#pragma unroll
      for (int nt = 0; nt < 3; nt++) acc[mt][nt] = f4zero();
#pragma unroll
    for (int kt = 0; kt < 6; kt++){
      bf16x8 a[4], bw[3];
#pragma unroll
      for (int nt = 0; nt < 3; nt++)
        bw[nt] = ldfrag(&wq[(size_t)(n0 + nt*16 + l16)*192 + kt*32 + quad*8]);
#pragma unroll
      for (int mt = 0; mt < 4; mt++)
        a[mt] = ldfrag(&xnb[(mt*16 + l16)*192 + ((kt*32 + quad*8) ^ ((l16 & 7) << 3))]);
#pragma unroll
      for (int mt = 0; mt < 4; mt++)
#pragma unroll
        for (int nt = 0; nt < 3; nt++)
          acc[mt][nt] = mfma16(a[mt], bw[nt], acc[mt][nt]);
    }
  };

  auto qkv_epi = [&](f32x4 (*acc)[3], int np){
    const int n0 = sec*192 + np*96 + sub*48;
    const float scale = 0.17677669529663687f;   // 1/sqrt(32)
#pragma unroll
    for (int nt = 0; nt < 3; nt++){
      const int bc = sub*48 + nt*16 + l16;      // 0..95 within section
      const int hl2 = bc >> 5, d = bc & 31;     // trio-local head, channel
      const float bias = qkv_b[n0 + nt*16 + l16];
#pragma unroll
      for (int mt = 0; mt < 4; mt++)
#pragma unroll
        for (int r = 0; r < 4; r++){
          const int row = mt*16 + quad*4 + r;
          const float val = acc[mt][nt][r] + bias;
          if (sec == 0)      qk[(hl2*64 + row)*72 + d]      = f2bf(val * scale);
          else if (sec == 1) qk[(hl2*64 + row)*72 + 32 + d] = f2bf(val);
          else               vt[(hl2*32 + d)*72 + row]      = f2bf(val);
        }
    }
  };

  // ---- attention round np (trio np): QK^T -> [SYNC] -> softmax -> PV -> O into ob ----
  auto attn_round = [&](int np){
    const int head = np*3 + hl;
    f32x4 bias4[2][4];
#pragma unroll
    for (int i = 0; i < 2; i++)
#pragma unroll
      for (int r = 0; r < 4; r++){
        const int t = half*32 + i*16 + quad*4 + r;
        bias4[i][r] = *(const f32x4*)&bt[head*4096 + t*64 + l16*4];
      }

    bf16x8 aq[2];
#pragma unroll
    for (int i = 0; i < 2; i++)
      aq[i] = ldfrag(&qk[(hl*64 + half*32 + i*16 + l16)*72 + quad*8]);

    f32x4 s[2][4];
#pragma unroll
    for (int nt = 0; nt < 4; nt++){
      bf16x8 bk = ldfrag(&qk[(hl*64 + nt*16 + l16)*72 + 32 + quad*8]);
#pragma unroll
      for (int i = 0; i < 2; i++)
        s[i][nt] = mfma16(aq[i], bk, f4zero());
    }

    __syncthreads();   // all QK reads done -> P overlay of Q|K region is safe

    float linv[2][4];
#pragma unroll
    for (int i = 0; i < 2; i++)
#pragma unroll
      for (int r = 0; r < 4; r++){
        const f32x4 b4 = bias4[i][r];
#pragma unroll
        for (int nt = 0; nt < 4; nt++) s[i][nt][r] += b4[nt];
        float m = fmaxf(fmaxf(s[i][0][r], s[i][1][r]), fmaxf(s[i][2][r], s[i][3][r]));
#pragma unroll
        for (int off = 8; off > 0; off >>= 1) m = fmaxf(m, __shfl_xor(m, off));
        float l = 0.f;
        const int t = half*32 + i*16 + quad*4 + r;
#pragma unroll
        for (int nt = 0; nt < 4; nt++){
          float pexp = __expf(s[i][nt][r] - m);
          l += pexp;
          qk[hl*4608 + t*72 + nt*16 + l16] = f2bf(pexp);
        }
#pragma unroll
        for (int off = 8; off > 0; off >>= 1) l += __shfl_xor(l, off);
        linv[i][r] = 1.f / l;
      }

    f32x4 o[2][2];
#pragma unroll
    for (int i = 0; i < 2; i++)
#pragma unroll
      for (int n2 = 0; n2 < 2; n2++) o[i][n2] = f4zero();
#pragma unroll
    for (int kt = 0; kt < 2; kt++){
      bf16x8 ap[2], bv[2];
#pragma unroll
      for (int i = 0; i < 2; i++)
        ap[i] = ldfrag(&qk[hl*4608 + (half*32 + i*16 + l16)*72 + kt*32 + quad*8]);
#pragma unroll
      for (int n2 = 0; n2 < 2; n2++)
        bv[n2] = ldfrag(&vt[(hl*32 + n2*16 + l16)*72 + kt*32 + quad*8]);
#pragma unroll
      for (int i = 0; i < 2; i++)
#pragma unroll
        for (int n2 = 0; n2 < 2; n2++)
          o[i][n2] = mfma16(ap[i], bv[n2], o[i][n2]);
    }

    // write O (all 64 rows; rows 49..63 finite garbage, confined to discarded out rows)
#pragma unroll
    for (int i = 0; i < 2; i++)
#pragma unroll
      for (int r = 0; r < 4; r++){
        const int t = half*32 + i*16 + quad*4 + r;
        const float inv = linv[i][r];
        ob[t*OBS + hl*32 + l16]      = f2bf(o[i][0][r] * inv);
        ob[t*OBS + hl*32 + 16 + l16] = f2bf(o[i][1][r] * inv);
      }
  };

  // ---- proj partial: pacc += O(ob, K-slice np*96..+96) x Wp ----
  auto proj_part = [&](f32x4 (*pacc)[2], int np){
#pragma unroll
    for (int kt = 0; kt < 3; kt++){
      bf16x8 a2[4], bw2[2];
#pragma unroll
      for (int n2 = 0; n2 < 2; n2++)
        bw2[n2] = ldfrag(&wp[(size_t)(wave*32 + n2*16 + l16)*192 + np*96 + kt*32 + quad*8]);
#pragma unroll
      for (int mt = 0; mt < 4; mt++)
        a2[mt] = ldfrag(&ob[(mt*16 + l16)*OBS + kt*32 + quad*8]);
#pragma unroll
      for (int mt = 0; mt < 4; mt++)
#pragma unroll
        for (int n2 = 0; n2 < 2; n2++)
          pacc[mt][n2] = mfma16(a2[mt], bw2[n2], pacc[mt][n2]);
    }
  };

  // ================= main flow =================
  f32x4 acc0[4][3], acc1[4][3];
  qkv_gemm(acc0, 0);
  qkv_epi (acc0, 0);           // trio0 -> qk/vt
  qkv_gemm(acc1, 1);           // trio1 held in registers
  __syncthreads();             // SYNC2: xnb reads done; trio0 visible

  attn_round(0);               // internal SYNC3; ends with O0 -> ob
  __syncthreads();             // SYNC4: ob(O0) visible; all P/vt trio0 reads done

  qkv_epi(acc1, 1);            // trio1 -> qk/vt (overwrites trio0/P)
  f32x4 pacc[4][2];
#pragma unroll
  for (int mt = 0; mt < 4; mt++)
#pragma unroll
    for (int n2 = 0; n2 < 2; n2++) pacc[mt][n2] = f4zero();
  proj_part(pacc, 0);          // reads ob(O0)
  __syncthreads();             // SYNC5: trio1 visible; ob reads done

  attn_round(1);               // internal SYNC6; ends with O1 -> ob
  __syncthreads();             // SYNC7: ob(O1) visible

  proj_part(pacc, 1);

  // ---- store out fp32, window reverse, rows < 49 ----
#pragma unroll
  for (int n2 = 0; n2 < 2; n2++){
    const float bias = n2 ? pbv1 : pbv0;
#pragma unroll
    for (int mt = 0; mt < 4; mt++)
#pragma unroll
      for (int r = 0; r < 4; r++){
        const int t = mt*16 + quad*4 + r;
        if (t < 49){
          const int tr = div7(t), tcc = t - tr*7;
          const size_t base =
            ((size_t)b*3136 + (size_t)((wr*7 + tr)*56 + wc*7 + tcc))*192
            + wave*32 + n2*16 + l16;
          out[base] = pacc[mt][n2][r] + bias;
        }
      }
  }
}

extern "C" void kernel_launch(void* const* d_in, const int* in_sizes, int n_in,
                              void* d_out, int out_size, void* d_ws, size_t ws_size,
                              hipStream_t stream) {
  (void)in_sizes; (void)n_in; (void)out_size; (void)ws_size;
  const float* x      = (const float*)d_in[0];
  const float* gamma  = (const float*)d_in[1];
  const float* rpb    = (const float*)d_in[2];
  const float* qkv_w  = (const float*)d_in[3];
  const float* qkv_b  = (const float*)d_in[4];
  const float* proj_w = (const float*)d_in[5];
  const float* proj_b = (const float*)d_in[6];

  unsigned short* wq  = (unsigned short*)d_ws;             // 576*192 bf16
  unsigned short* wp  = wq + 576*192;                      // 192*192 bf16
  float* bt           = (float*)(wp + 192*192);            // 6*64*64 fp32 (transposed)
  unsigned short* xng = (unsigned short*)(bt + 6*64*64);   // 2048*49*192 bf16 (compact,
                                                           // row-swizzled) = 38.5MB,
                                                           // same slot attn used to occupy
  float* out = (float*)d_out;

  hipLaunchKernelGGL(wa_ln, dim3(2048), dim3(256), 0, stream,
                     x, gamma, xng, qkv_w, proj_w, rpb, wq, wp, bt);
  hipLaunchKernelGGL(wa_k1, dim3(2048), dim3(384), 0, stream,
                     xng, bt, wq, qkv_b, wp, proj_b, out);
}